// Round 13
// baseline (142.219 us; speedup 1.0000x reference)
//
#include <hip/hip_runtime.h>
#include <hip/hip_bf16.h>

typedef float f4vec  __attribute__((ext_vector_type(4)));
typedef float f16vec __attribute__((ext_vector_type(16)));
typedef short s8vec  __attribute__((ext_vector_type(8)));

#define B_DIM 64
#define N_DIM 64
#define D_DIM 9216
#define SPLIT 8
#define CHUNK 1152          // D_DIM / SPLIT
#define NSTEP (CHUNK / 64)  // 18

// ws layout (bytes):
//   Spart    @ 0        : 64*8*4096*4 = 8388608
//   meanPart @ 8388608  : 64*8*64*4   = 131072
//   Cout     @ 8519680  : 64*64*4     = 16384   (c = inv_L @ mean, fp32)
//   Mb(bf16) @ 8536064  : 64*4096*2   = 524288  (M = inv_L - I, row-major)

__device__ __forceinline__ short f2bf(float f) {
  union { __hip_bfloat16 h; short s; } u;
  u.h = __float2bfloat16(f);
  return u.s;
}

// v_readlane: static VGPR, manifestly-uniform (loop-scalar) lane index ONLY.
__device__ __forceinline__ float rdlane(float v, int l) {
  union { float f; int i; } u;
  u.f = v;
  u.i = __builtin_amdgcn_readlane(u.i, l);
  return u.f;
}

// ---------------- Kernel 1: partial Gram + row-sum partials ----------------
__global__ __launch_bounds__(256) void k_cov_partial(
    const float* __restrict__ x, float* __restrict__ Spart,
    float* __restrict__ meanPart) {
  const int s = blockIdx.x, b = blockIdx.y;
  const int t = threadIdx.x;
  const int lane = t & 63, w = t >> 6;
  const int wr = w >> 1, wc = w & 1;
  const int hi = lane >> 5;

  __shared__ float T[64 * 64];

  const float* xb = x + (size_t)b * N_DIM * D_DIM + (size_t)s * CHUNK;
  const int jrow = t >> 2, q = t & 3;
  const float* xrow = xb + (size_t)jrow * D_DIM;

  f16vec acc;
#pragma unroll
  for (int r = 0; r < 16; ++r) acc[r] = 0.0f;
  float msum = 0.0f;

  const int r_a = 32 * wr + (lane & 31);
  const int r_b = 32 * wc + (lane & 31);

  f4vec v[4];
#pragma unroll
  for (int i = 0; i < 4; ++i)
    v[i] = *reinterpret_cast<const f4vec*>(xrow + (i * 4 + q) * 4);

  for (int step = 0; step < NSTEP; ++step) {
    __syncthreads();  // previous step's frag reads done; LDS free
#pragma unroll
    for (int i = 0; i < 4; ++i) {
      const int f = i * 4 + q;
      msum += v[i].x + v[i].y + v[i].z + v[i].w;
      *reinterpret_cast<f4vec*>(&T[jrow * 64 + ((f ^ (jrow & 15)) << 2)]) = v[i];
    }
    __syncthreads();  // tile ready
    if (step + 1 < NSTEP) {
      const float* xn = xrow + (step + 1) * 64;
#pragma unroll
      for (int i = 0; i < 4; ++i)
        v[i] = *reinterpret_cast<const f4vec*>(xn + (i * 4 + q) * 4);
    }
#pragma unroll
    for (int ks = 0; ks < 4; ++ks) {
      const int c0 = ks * 4 + hi * 2;
      f4vec a0 = *reinterpret_cast<const f4vec*>(
          &T[r_a * 64 + ((c0 ^ (r_a & 15)) << 2)]);
      f4vec a1 = *reinterpret_cast<const f4vec*>(
          &T[r_a * 64 + (((c0 + 1) ^ (r_a & 15)) << 2)]);
      f4vec b0 = *reinterpret_cast<const f4vec*>(
          &T[r_b * 64 + ((c0 ^ (r_b & 15)) << 2)]);
      f4vec b1 = *reinterpret_cast<const f4vec*>(
          &T[r_b * 64 + (((c0 + 1) ^ (r_b & 15)) << 2)]);
      s8vec af, bf;
      af[0]=f2bf(a0.x); af[1]=f2bf(a0.y); af[2]=f2bf(a0.z); af[3]=f2bf(a0.w);
      af[4]=f2bf(a1.x); af[5]=f2bf(a1.y); af[6]=f2bf(a1.z); af[7]=f2bf(a1.w);
      bf[0]=f2bf(b0.x); bf[1]=f2bf(b0.y); bf[2]=f2bf(b0.z); bf[3]=f2bf(b0.w);
      bf[4]=f2bf(b1.x); bf[5]=f2bf(b1.y); bf[6]=f2bf(b1.z); bf[7]=f2bf(b1.w);
      acc = __builtin_amdgcn_mfma_f32_32x32x16_bf16(af, bf, acc, 0, 0, 0);
    }
  }

  msum += __shfl_xor(msum, 1);
  msum += __shfl_xor(msum, 2);
  if (q == 0) meanPart[(b * SPLIT + s) * 64 + jrow] = msum;

  float* Sp = Spart + (size_t)(b * SPLIT + s) * 4096;
#pragma unroll
  for (int r = 0; r < 16; ++r) {
    const int i = 32 * wr + (r & 3) + 8 * (r >> 2) + 4 * hi;
    const int j = 32 * wc + (lane & 31);
    Sp[i * 64 + j] = acc[r];
  }
}

// ------ Kernel 2: blocked Cholesky + BLOCKED triangular inverse ------------
// ROUND 13: byte-identical to r12. The launcher runs this kernel 4x (it is
// idempotent) purely to measure its true duration: k2 = (dur - 100.2)/3.
// Three k2-internals theories in a row were falsified while relying on an
// inferred k2 ~= 48 us; the cycle model says 10-15. This round decides.
__global__ __launch_bounds__(256) void k_chol_inv(
    const float* __restrict__ Spart, const float* __restrict__ meanPart,
    unsigned short* __restrict__ Mb, float* __restrict__ Cout) {
  const int t = threadIdx.x;
  const int b = blockIdx.x;
  const int wid = t >> 6, lane = t & 63;

  __shared__ float Ash[64 * 68];   // A-bar (lower valid), pitch 68
  __shared__ float Ysh[64 * 68];   // Y = inv(A-bar), lower; upper zeroed
  __shared__ float Prow[4][8 * 64];// per-wave staged pivot columns (8 KB)
  __shared__ float Tsh[1056];      // level scratch (32x33 max)
  __shared__ float mean_sh[64];
  __shared__ float sqd_sh[64];

  if (t < 64) {
    float mm = 0.0f;
#pragma unroll
    for (int p = 0; p < SPLIT; ++p) mm += meanPart[(b * SPLIT + p) * 64 + t];
    mean_sh[t] = mm * (1.0f / D_DIM);
  }
  __syncthreads();

  // cov reduce: thread t handles f4-chunks f = t + 256*m (coalesced loads).
  {
    const float invD1 = 1.0f / (float)(D_DIM - 1);
    const f4vec* Sp =
        reinterpret_cast<const f4vec*>(Spart + (size_t)(b * SPLIT) * 4096);
#pragma unroll
    for (int m = 0; m < 4; ++m) {
      const int f = t + 256 * m;
      f4vec s = Sp[f];
#pragma unroll
      for (int p = 1; p < SPLIT; ++p) s += Sp[p * 1024 + f];
      const int row = f >> 4, c4 = f & 15;
      const float miD = mean_sh[row] * (float)D_DIM;
      const f4vec mj = *reinterpret_cast<const f4vec*>(&mean_sh[c4 * 4]);
      f4vec r;
      r.x = (s.x - miD * mj.x) * invD1;
      r.y = (s.y - miD * mj.y) * invD1;
      r.z = (s.z - miD * mj.z) * invD1;
      r.w = (s.w - miD * mj.w) * invD1;
      *reinterpret_cast<f4vec*>(&Ash[row * 68 + c4 * 4]) = r;
    }
  }
  __syncthreads();

  // ---- Blocked Cholesky: 8 panels x 8 cols; ONE barrier per panel. ----
#pragma clang loop unroll(disable)
  for (int kb = 0; kb < 8; ++kb) {
    const int K = kb * 8;
    float p[8];
    {
      f4vec pa = *reinterpret_cast<const f4vec*>(&Ash[lane * 68 + K]);
      f4vec pb = *reinterpret_cast<const f4vec*>(&Ash[lane * 68 + K + 4]);
      p[0]=pa.x; p[1]=pa.y; p[2]=pa.z; p[3]=pa.w;
      p[4]=pb.x; p[5]=pb.y; p[6]=pb.z; p[7]=pb.w;
    }
    float fl[8];
#pragma unroll
    for (int c = 0; c < 8; ++c) {
      const int kc = K + c;                 // loop-scalar: uniform readlane
      Prow[wid][c * 64 + lane] = p[c];      // stage finalized column c
      const float d = rdlane(p[c], kc);
      const float inv = __builtin_amdgcn_rcpf(d);
      const float f = (lane > kc) ? p[c] * inv : 0.0f;
      fl[c] = f;
#pragma unroll
      for (int j = c + 1; j < 8; ++j)
        p[j] -= f * rdlane(p[j], kc);
    }
    if (wid == (kb >> 1)) {
      f4vec pa, pb;
      pa.x=p[0]; pa.y=p[1]; pa.z=p[2]; pa.w=p[3];
      pb.x=p[4]; pb.y=p[5]; pb.z=p[6]; pb.w=p[7];
      *reinterpret_cast<f4vec*>(&Ash[lane * 68 + K]) = pa;
      *reinterpret_cast<f4vec*>(&Ash[lane * 68 + K + 4]) = pb;
    }
    // Trailing rank-8 update via per-wave staged pivot columns (broadcast
    // f4 LDS reads, waterfall-free).
#pragma unroll
    for (int q = 0; q < 4; ++q) {
      const int j0 = 16 * wid + 4 * q;
      if (j0 >= K + 8) {                      // wave-uniform branch
        f4vec o = *reinterpret_cast<const f4vec*>(&Ash[lane * 68 + j0]);
        float sx = 0.0f, sy = 0.0f, sz = 0.0f, sw = 0.0f;
#pragma unroll
        for (int c = 0; c < 8; ++c) {
          const f4vec rk =
              *reinterpret_cast<const f4vec*>(&Prow[wid][c * 64 + j0]);
          sx += fl[c] * rk.x;
          sy += fl[c] * rk.y;
          sz += fl[c] * rk.z;
          sw += fl[c] * rk.w;
        }
        o.x -= sx; o.y -= sy; o.z -= sz; o.w -= sw;
        *reinterpret_cast<f4vec*>(&Ash[lane * 68 + j0]) = o;
      }
    }
    __syncthreads();
  }

  // ---- Zero Y (upper blocks must read as exact 0) + sqrt(diag). ----
  {
    f4vec z; z.x = z.y = z.z = z.w = 0.0f;
    for (int e = t; e < 64 * 17; e += 256)
      *reinterpret_cast<f4vec*>(&Ysh[e * 4]) = z;
    if (t < 64) sqd_sh[t] = __builtin_amdgcn_sqrtf(Ash[t * 68 + t]);
  }
  __syncthreads();

  // ---- L0: invert 8 diagonal 8x8 blocks (thread = (block q, column cL)) --
  if (t < 64) {
    const int q = t >> 3, cL = t & 7, base = q * 8;
    float yv[8];
#pragma unroll
    for (int i = 0; i < 8; ++i) yv[i] = 0.0f;
#pragma unroll
    for (int i = 0; i < 8; ++i) {
      float s = 0.0f;
#pragma unroll
      for (int j = 0; j < 8; ++j)
        if (j < i) s += Ash[(base + i) * 68 + base + j] * yv[j];
      const float del = (i == cL) ? 1.0f : 0.0f;
      float yi = (del - s) * __builtin_amdgcn_rcpf(Ash[(base + i) * 68 + base + i]);
      yi = (i >= cL) ? yi : 0.0f;   // strictly-upper of block = 0
      yv[i] = yi;
      Ysh[(base + i) * 68 + base + cL] = yi;
    }
  }
  __syncthreads();

  // ---- L1: 4 pairs at 16-granularity; wave p owns pair p. ----
  {
    const int p = wid, e = t & 63, r = e >> 3, cc = e & 7;
    const int R = p * 16 + 8 + r, J = p * 16;
    // step A: T = A21 * Y11  (8x8x8)
    float s = 0.0f;
    {
      f4vec a0 = *reinterpret_cast<const f4vec*>(&Ash[R * 68 + J]);
      f4vec a1 = *reinterpret_cast<const f4vec*>(&Ash[R * 68 + J + 4]);
      s += a0.x * Ysh[(J + 0) * 68 + J + cc] + a0.y * Ysh[(J + 1) * 68 + J + cc]
         + a0.z * Ysh[(J + 2) * 68 + J + cc] + a0.w * Ysh[(J + 3) * 68 + J + cc];
      s += a1.x * Ysh[(J + 4) * 68 + J + cc] + a1.y * Ysh[(J + 5) * 68 + J + cc]
         + a1.z * Ysh[(J + 6) * 68 + J + cc] + a1.w * Ysh[(J + 7) * 68 + J + cc];
    }
    Tsh[p * 264 + r * 33 + cc] = s;
    __syncthreads();
    // step B: Y21 = -Y22 * T
    float s2 = 0.0f;
    {
      f4vec y0 = *reinterpret_cast<const f4vec*>(&Ysh[R * 68 + J + 8]);
      f4vec y1 = *reinterpret_cast<const f4vec*>(&Ysh[R * 68 + J + 12]);
      const float* Tc = &Tsh[p * 264 + cc];
      s2 += y0.x * Tc[0 * 33] + y0.y * Tc[1 * 33]
          + y0.z * Tc[2 * 33] + y0.w * Tc[3 * 33];
      s2 += y1.x * Tc[4 * 33] + y1.y * Tc[5 * 33]
          + y1.z * Tc[6 * 33] + y1.w * Tc[7 * 33];
    }
    __syncthreads();               // Tsh reuse at L2
    Ysh[R * 68 + J + cc] = -s2;
  }
  __syncthreads();

  // ---- L2: 2 pairs at 32-granularity; waves {0,1}->pair0, {2,3}->pair1. --
  {
    const int p = t >> 7, tid = t & 127;
    // step A: T = A21 * Y11  (16x16x16), 2 elems/thread
    float sa[2];
#pragma unroll
    for (int m = 0; m < 2; ++m) {
      const int E = tid + 128 * m, r = E >> 4, cc = E & 15;
      const int R = p * 32 + 16 + r, J = p * 32;
      float s = 0.0f;
#pragma unroll
      for (int k4 = 0; k4 < 4; ++k4) {
        f4vec a = *reinterpret_cast<const f4vec*>(&Ash[R * 68 + J + k4 * 4]);
        const int k = k4 * 4;
        s += a.x * Ysh[(J + k + 0) * 68 + J + cc]
           + a.y * Ysh[(J + k + 1) * 68 + J + cc]
           + a.z * Ysh[(J + k + 2) * 68 + J + cc]
           + a.w * Ysh[(J + k + 3) * 68 + J + cc];
      }
      sa[m] = s;
    }
#pragma unroll
    for (int m = 0; m < 2; ++m) {
      const int E = tid + 128 * m, r = E >> 4, cc = E & 15;
      Tsh[p * 528 + r * 33 + cc] = sa[m];
    }
    __syncthreads();
    // step B: Y21 = -Y22 * T
    float sb[2];
#pragma unroll
    for (int m = 0; m < 2; ++m) {
      const int E = tid + 128 * m, r = E >> 4, cc = E & 15;
      const int R = p * 32 + 16 + r, J = p * 32;
      float s = 0.0f;
      const float* Tc = &Tsh[p * 528 + cc];
#pragma unroll
      for (int k4 = 0; k4 < 4; ++k4) {
        f4vec y = *reinterpret_cast<const f4vec*>(&Ysh[R * 68 + J + 16 + k4 * 4]);
        const int k = k4 * 4;
        s += y.x * Tc[(k + 0) * 33] + y.y * Tc[(k + 1) * 33]
           + y.z * Tc[(k + 2) * 33] + y.w * Tc[(k + 3) * 33];
      }
      sb[m] = s;
    }
    __syncthreads();               // Tsh reuse at L3
#pragma unroll
    for (int m = 0; m < 2; ++m) {
      const int E = tid + 128 * m, r = E >> 4, cc = E & 15;
      const int R = p * 32 + 16 + r, J = p * 32;
      Ysh[R * 68 + J + cc] = -sb[m];
    }
  }
  __syncthreads();

  // ---- L3: final pair (rows 32..63, cols 0..31), 4 elems/thread. ----
  {
    // step A: T = A21 * Y11  (32x32x32)
    float sa[4];
#pragma unroll
    for (int m = 0; m < 4; ++m) {
      const int E = t + 256 * m, r = E >> 5, cc = E & 31;
      const int R = 32 + r;
      float s = 0.0f;
#pragma unroll
      for (int k4 = 0; k4 < 8; ++k4) {
        f4vec a = *reinterpret_cast<const f4vec*>(&Ash[R * 68 + k4 * 4]);
        const int k = k4 * 4;
        s += a.x * Ysh[(k + 0) * 68 + cc] + a.y * Ysh[(k + 1) * 68 + cc]
           + a.z * Ysh[(k + 2) * 68 + cc] + a.w * Ysh[(k + 3) * 68 + cc];
      }
      sa[m] = s;
    }
#pragma unroll
    for (int m = 0; m < 4; ++m) {
      const int E = t + 256 * m, r = E >> 5, cc = E & 31;
      Tsh[r * 33 + cc] = sa[m];
    }
    __syncthreads();
    // step B: Y21 = -Y22 * T
    float sb[4];
#pragma unroll
    for (int m = 0; m < 4; ++m) {
      const int E = t + 256 * m, r = E >> 5, cc = E & 31;
      const int R = 32 + r;
      float s = 0.0f;
      const float* Tc = &Tsh[cc];
#pragma unroll
      for (int k4 = 0; k4 < 8; ++k4) {
        f4vec y = *reinterpret_cast<const f4vec*>(&Ysh[R * 68 + 32 + k4 * 4]);
        const int k = k4 * 4;
        s += y.x * Tc[(k + 0) * 33] + y.y * Tc[(k + 1) * 33]
           + y.z * Tc[(k + 2) * 33] + y.w * Tc[(k + 3) * 33];
      }
      sb[m] = s;
    }
#pragma unroll
    for (int m = 0; m < 4; ++m) {
      const int E = t + 256 * m, r = E >> 5, cc = E & 31;
      Ysh[(32 + r) * 68 + cc] = -sb[m];
    }
  }
  __syncthreads();

  // ---- Epilogue: Mb = bf16(inv_L - I), Cvec = inv_L @ mean. ----
  const size_t mb_base = (size_t)b * 4096;
#pragma unroll
  for (int m = 0; m < 16; ++m) {
    const int e = t + 256 * m, i = e >> 6, j = e & 63;
    float v = 0.0f;
    if (j <= i) {
      v = sqd_sh[i] * Ysh[i * 68 + j];
      if (j == i) v -= 1.0f;
    }
    Mb[mb_base + e] = (unsigned short)f2bf(v);
  }
  {
    const int i2 = t >> 2, g = t & 3;
    float pz = 0.0f;
#pragma unroll
    for (int s2 = 0; s2 < 16; ++s2) {
      const int cc = g + 4 * s2;
      pz += Ysh[i2 * 68 + cc] * mean_sh[cc];
    }
    pz += __shfl_xor(pz, 1);
    pz += __shfl_xor(pz, 2);
    if (g == 0) Cout[b * 64 + i2] = pz * sqd_sh[i2];
  }
}

// ---------------- Kernel 3: out = x + M@x - c*1^T  (LDS-free) --------------
__global__ __launch_bounds__(256) void k_whiten(
    const float* __restrict__ x, const float* __restrict__ Cvec,
    const unsigned short* __restrict__ Mb, float* __restrict__ out) {
  const int b = blockIdx.y;
  const int t = threadIdx.x;
  const int wid = t >> 6, lane = t & 63;
  const int lo = lane & 31, hi = lane >> 5;

  s8vec mfrag[2][4];
  const unsigned short* Mbb = Mb + (size_t)b * 4096;
#pragma unroll
  for (int wr = 0; wr < 2; ++wr)
#pragma unroll
    for (int ks = 0; ks < 4; ++ks)
      mfrag[wr][ks] = *reinterpret_cast<const s8vec*>(
          Mbb + (32 * wr + lo) * 64 + ks * 16 + hi * 8);

  float cv[2][16];
  const float* cb = Cvec + b * 64;
#pragma unroll
  for (int wr = 0; wr < 2; ++wr)
#pragma unroll
    for (int r = 0; r < 16; ++r)
      cv[wr][r] = cb[32 * wr + (r & 3) + 8 * (r >> 2) + 4 * hi];

  const float* xb = x + (size_t)b * N_DIM * D_DIM;
  float* ob = out + (size_t)b * N_DIM * D_DIM;

#pragma unroll
  for (int n = 0; n < 2; ++n) {
    const int d0 = blockIdx.x * 256 + wid * 64 + n * 32;
    f16vec acc0, acc1;
#pragma unroll
    for (int r = 0; r < 16; ++r) { acc0[r] = 0.0f; acc1[r] = 0.0f; }

#pragma unroll
    for (int ks = 0; ks < 4; ++ks) {
      const float* colp = xb + (size_t)(16 * ks + 8 * hi) * D_DIM + d0 + lo;
      s8vec bf;
#pragma unroll
      for (int e = 0; e < 8; ++e) bf[e] = f2bf(colp[(size_t)e * D_DIM]);
      acc0 = __builtin_amdgcn_mfma_f32_32x32x16_bf16(mfrag[0][ks], bf, acc0, 0, 0, 0);
      acc1 = __builtin_amdgcn_mfma_f32_32x32x16_bf16(mfrag[1][ks], bf, acc1, 0, 0, 0);
    }

#pragma unroll
    for (int r = 0; r < 16; ++r) {
      const int row = (r & 3) + 8 * (r >> 2) + 4 * hi;
      const size_t off0 = (size_t)row * D_DIM + d0 + lo;
      ob[off0] = acc0[r] + xb[off0] - cv[0][r];
      const size_t off1 = (size_t)(row + 32) * D_DIM + d0 + lo;
      ob[off1] = acc1[r] + xb[off1] - cv[1][r];
    }
  }
}

extern "C" void kernel_launch(void* const* d_in, const int* in_sizes, int n_in,
                              void* d_out, int out_size, void* d_ws,
                              size_t ws_size, hipStream_t stream) {
  const float* x = (const float*)d_in[0];
  float* out = (float*)d_out;
  char* ws = (char*)d_ws;

  float* Spart = (float*)ws;                            // 8 MB
  float* meanPart = (float*)(ws + 8388608);             // 128 KB
  float* Cout = (float*)(ws + 8519680);                 // 16 KB
  unsigned short* Mb = (unsigned short*)(ws + 8536064); // 512 KB

  k_cov_partial<<<dim3(SPLIT, B_DIM), 256, 0, stream>>>(x, Spart, meanPart);
  // MEASUREMENT (r13): run k2 4x. It is idempotent (reads k1 outputs,
  // rewrites identical Mb/Cout). k2_duration = (total - 100.2us)/3.
  for (int rep = 0; rep < 4; ++rep)
    k_chol_inv<<<dim3(B_DIM), 256, 0, stream>>>(Spart, meanPart, Mb, Cout);
  k_whiten<<<dim3(D_DIM / 256, B_DIM), 256, 0, stream>>>(x, Cout, Mb, out);
}

// Round 14
// 94.075 us; speedup vs baseline: 1.5118x; 1.5118x over previous
//
#include <hip/hip_runtime.h>
#include <hip/hip_bf16.h>

typedef float f4vec  __attribute__((ext_vector_type(4)));
typedef float f16vec __attribute__((ext_vector_type(16)));
typedef short s8vec  __attribute__((ext_vector_type(8)));

#define B_DIM 64
#define N_DIM 64
#define D_DIM 9216
#define SPLIT 8
#define CHUNK 1152          // D_DIM / SPLIT
#define NSTEP (CHUNK / 64)  // 18

// ws layout (bytes):
//   Spart    @ 0        : 64*8*4096*4 = 8388608
//   meanPart @ 8388608  : 64*8*64*4   = 131072
//   Cout     @ 8519680  : 64*64*4     = 16384   (c = inv_L @ mean, fp32)
//   Mb(bf16) @ 8536064  : 64*4096*2   = 524288  (M = inv_L - I, row-major)

__device__ __forceinline__ short f2bf(float f) {
  union { __hip_bfloat16 h; short s; } u;
  u.h = __float2bfloat16(f);
  return u.s;
}

__device__ __forceinline__ unsigned int pack_bf2(float lo, float hi) {
  return (unsigned int)(unsigned short)f2bf(lo) |
         ((unsigned int)(unsigned short)f2bf(hi) << 16);
}

// v_readlane: static VGPR, manifestly-uniform (loop-scalar) lane index ONLY.
__device__ __forceinline__ float rdlane(float v, int l) {
  union { float f; int i; } u;
  u.f = v;
  u.i = __builtin_amdgcn_readlane(u.i, l);
  return u.f;
}

// ---------------- Kernel 1: partial Gram + row-sum partials ----------------
// r14: LDS tile holds BF16 pairs (8 KB), converted ONCE at stage time.
// Tile layout: row-major [64 rows][32 u32-pairs], 16B chunks XOR-swizzled
// ch ^= (row&7) -> frag ds_read_b128 is conflict-free (8 rows tile all 32
// banks). MFMA loop: 8 ds_read_b128 + 4 MFMA, zero cvt (was 16 fp32 b128
// reads + 64 f2bf per thread per step). Same values converted -> Spart
// bit-identical to r12.
__global__ __launch_bounds__(256) void k_cov_partial(
    const float* __restrict__ x, float* __restrict__ Spart,
    float* __restrict__ meanPart) {
  const int s = blockIdx.x, b = blockIdx.y;
  const int t = threadIdx.x;
  const int lane = t & 63, w = t >> 6;
  const int wr = w >> 1, wc = w & 1;
  const int hi = lane >> 5;

  __shared__ unsigned int T[64 * 32];   // bf16-pair tile, 8 KB

  const float* xb = x + (size_t)b * N_DIM * D_DIM + (size_t)s * CHUNK;
  const int jrow = t >> 2, q = t & 3;
  const float* xrow = xb + (size_t)jrow * D_DIM;

  f16vec acc;
#pragma unroll
  for (int r = 0; r < 16; ++r) acc[r] = 0.0f;
  float msum = 0.0f;

  const int r_a = 32 * wr + (lane & 31);
  const int r_b = 32 * wc + (lane & 31);

  f4vec v[4];
#pragma unroll
  for (int i = 0; i < 4; ++i)
    v[i] = *reinterpret_cast<const f4vec*>(xrow + (i * 4 + q) * 4);

  for (int step = 0; step < NSTEP; ++step) {
    __syncthreads();  // previous step's frag reads done; LDS free
#pragma unroll
    for (int i = 0; i < 4; ++i) {
      msum += v[i].x + v[i].y + v[i].z + v[i].w;
      // cols i*16 + q*4 .. +3 -> pairs 8i+2q, 8i+2q+1
      const unsigned int p0 = pack_bf2(v[i].x, v[i].y);
      const unsigned int p1 = pack_bf2(v[i].z, v[i].w);
      const int ch = 2 * i + (q >> 1);
      const int slot = (q & 1) * 2;
      unsigned int* dst = &T[jrow * 32 + ((ch ^ (jrow & 7)) << 2) + slot];
      dst[0] = p0;
      dst[1] = p1;
    }
    __syncthreads();  // tile ready
    if (step + 1 < NSTEP) {
      const float* xn = xrow + (step + 1) * 64;
#pragma unroll
      for (int i = 0; i < 4; ++i)
        v[i] = *reinterpret_cast<const f4vec*>(xn + (i * 4 + q) * 4);
    }
#pragma unroll
    for (int ks = 0; ks < 4; ++ks) {
      const int chA = 2 * ks + hi;  // k = ks*16 + hi*8 + 0..7
      s8vec af = *reinterpret_cast<const s8vec*>(
          &T[r_a * 32 + ((chA ^ (r_a & 7)) << 2)]);
      s8vec bf = *reinterpret_cast<const s8vec*>(
          &T[r_b * 32 + ((chA ^ (r_b & 7)) << 2)]);
      acc = __builtin_amdgcn_mfma_f32_32x32x16_bf16(af, bf, acc, 0, 0, 0);
    }
  }

  msum += __shfl_xor(msum, 1);
  msum += __shfl_xor(msum, 2);
  if (q == 0) meanPart[(b * SPLIT + s) * 64 + jrow] = msum;

  float* Sp = Spart + (size_t)(b * SPLIT + s) * 4096;
#pragma unroll
  for (int r = 0; r < 16; ++r) {
    const int i = 32 * wr + (r & 3) + 8 * (r >> 2) + 4 * hi;
    const int j = 32 * wc + (lane & 31);
    Sp[i * 64 + j] = acc[r];
  }
}

// ------ Kernel 2: blocked Cholesky + BLOCKED triangular inverse ------------
// Byte-identical to r12 (measured 14 us in r13; near its ~8 us floor).
__global__ __launch_bounds__(256) void k_chol_inv(
    const float* __restrict__ Spart, const float* __restrict__ meanPart,
    unsigned short* __restrict__ Mb, float* __restrict__ Cout) {
  const int t = threadIdx.x;
  const int b = blockIdx.x;
  const int wid = t >> 6, lane = t & 63;

  __shared__ float Ash[64 * 68];   // A-bar (lower valid), pitch 68
  __shared__ float Ysh[64 * 68];   // Y = inv(A-bar), lower; upper zeroed
  __shared__ float Prow[4][8 * 64];// per-wave staged pivot columns (8 KB)
  __shared__ float Tsh[1056];      // level scratch (32x33 max)
  __shared__ float mean_sh[64];
  __shared__ float sqd_sh[64];

  if (t < 64) {
    float mm = 0.0f;
#pragma unroll
    for (int p = 0; p < SPLIT; ++p) mm += meanPart[(b * SPLIT + p) * 64 + t];
    mean_sh[t] = mm * (1.0f / D_DIM);
  }
  __syncthreads();

  // cov reduce: thread t handles f4-chunks f = t + 256*m (coalesced loads).
  {
    const float invD1 = 1.0f / (float)(D_DIM - 1);
    const f4vec* Sp =
        reinterpret_cast<const f4vec*>(Spart + (size_t)(b * SPLIT) * 4096);
#pragma unroll
    for (int m = 0; m < 4; ++m) {
      const int f = t + 256 * m;
      f4vec s = Sp[f];
#pragma unroll
      for (int p = 1; p < SPLIT; ++p) s += Sp[p * 1024 + f];
      const int row = f >> 4, c4 = f & 15;
      const float miD = mean_sh[row] * (float)D_DIM;
      const f4vec mj = *reinterpret_cast<const f4vec*>(&mean_sh[c4 * 4]);
      f4vec r;
      r.x = (s.x - miD * mj.x) * invD1;
      r.y = (s.y - miD * mj.y) * invD1;
      r.z = (s.z - miD * mj.z) * invD1;
      r.w = (s.w - miD * mj.w) * invD1;
      *reinterpret_cast<f4vec*>(&Ash[row * 68 + c4 * 4]) = r;
    }
  }
  __syncthreads();

  // ---- Blocked Cholesky: 8 panels x 8 cols; ONE barrier per panel. ----
#pragma clang loop unroll(disable)
  for (int kb = 0; kb < 8; ++kb) {
    const int K = kb * 8;
    float p[8];
    {
      f4vec pa = *reinterpret_cast<const f4vec*>(&Ash[lane * 68 + K]);
      f4vec pb = *reinterpret_cast<const f4vec*>(&Ash[lane * 68 + K + 4]);
      p[0]=pa.x; p[1]=pa.y; p[2]=pa.z; p[3]=pa.w;
      p[4]=pb.x; p[5]=pb.y; p[6]=pb.z; p[7]=pb.w;
    }
    float fl[8];
#pragma unroll
    for (int c = 0; c < 8; ++c) {
      const int kc = K + c;                 // loop-scalar: uniform readlane
      Prow[wid][c * 64 + lane] = p[c];      // stage finalized column c
      const float d = rdlane(p[c], kc);
      const float inv = __builtin_amdgcn_rcpf(d);
      const float f = (lane > kc) ? p[c] * inv : 0.0f;
      fl[c] = f;
#pragma unroll
      for (int j = c + 1; j < 8; ++j)
        p[j] -= f * rdlane(p[j], kc);
    }
    if (wid == (kb >> 1)) {
      f4vec pa, pb;
      pa.x=p[0]; pa.y=p[1]; pa.z=p[2]; pa.w=p[3];
      pb.x=p[4]; pb.y=p[5]; pb.z=p[6]; pb.w=p[7];
      *reinterpret_cast<f4vec*>(&Ash[lane * 68 + K]) = pa;
      *reinterpret_cast<f4vec*>(&Ash[lane * 68 + K + 4]) = pb;
    }
    // Trailing rank-8 update via per-wave staged pivot columns (broadcast
    // f4 LDS reads, waterfall-free).
#pragma unroll
    for (int q = 0; q < 4; ++q) {
      const int j0 = 16 * wid + 4 * q;
      if (j0 >= K + 8) {                      // wave-uniform branch
        f4vec o = *reinterpret_cast<const f4vec*>(&Ash[lane * 68 + j0]);
        float sx = 0.0f, sy = 0.0f, sz = 0.0f, sw = 0.0f;
#pragma unroll
        for (int c = 0; c < 8; ++c) {
          const f4vec rk =
              *reinterpret_cast<const f4vec*>(&Prow[wid][c * 64 + j0]);
          sx += fl[c] * rk.x;
          sy += fl[c] * rk.y;
          sz += fl[c] * rk.z;
          sw += fl[c] * rk.w;
        }
        o.x -= sx; o.y -= sy; o.z -= sz; o.w -= sw;
        *reinterpret_cast<f4vec*>(&Ash[lane * 68 + j0]) = o;
      }
    }
    __syncthreads();
  }

  // ---- Zero Y (upper blocks must read as exact 0) + sqrt(diag). ----
  {
    f4vec z; z.x = z.y = z.z = z.w = 0.0f;
    for (int e = t; e < 64 * 17; e += 256)
      *reinterpret_cast<f4vec*>(&Ysh[e * 4]) = z;
    if (t < 64) sqd_sh[t] = __builtin_amdgcn_sqrtf(Ash[t * 68 + t]);
  }
  __syncthreads();

  // ---- L0: invert 8 diagonal 8x8 blocks (thread = (block q, column cL)) --
  if (t < 64) {
    const int q = t >> 3, cL = t & 7, base = q * 8;
    float yv[8];
#pragma unroll
    for (int i = 0; i < 8; ++i) yv[i] = 0.0f;
#pragma unroll
    for (int i = 0; i < 8; ++i) {
      float s = 0.0f;
#pragma unroll
      for (int j = 0; j < 8; ++j)
        if (j < i) s += Ash[(base + i) * 68 + base + j] * yv[j];
      const float del = (i == cL) ? 1.0f : 0.0f;
      float yi = (del - s) * __builtin_amdgcn_rcpf(Ash[(base + i) * 68 + base + i]);
      yi = (i >= cL) ? yi : 0.0f;   // strictly-upper of block = 0
      yv[i] = yi;
      Ysh[(base + i) * 68 + base + cL] = yi;
    }
  }
  __syncthreads();

  // ---- L1: 4 pairs at 16-granularity; wave p owns pair p. ----
  {
    const int p = wid, e = t & 63, r = e >> 3, cc = e & 7;
    const int R = p * 16 + 8 + r, J = p * 16;
    // step A: T = A21 * Y11  (8x8x8)
    float s = 0.0f;
    {
      f4vec a0 = *reinterpret_cast<const f4vec*>(&Ash[R * 68 + J]);
      f4vec a1 = *reinterpret_cast<const f4vec*>(&Ash[R * 68 + J + 4]);
      s += a0.x * Ysh[(J + 0) * 68 + J + cc] + a0.y * Ysh[(J + 1) * 68 + J + cc]
         + a0.z * Ysh[(J + 2) * 68 + J + cc] + a0.w * Ysh[(J + 3) * 68 + J + cc];
      s += a1.x * Ysh[(J + 4) * 68 + J + cc] + a1.y * Ysh[(J + 5) * 68 + J + cc]
         + a1.z * Ysh[(J + 6) * 68 + J + cc] + a1.w * Ysh[(J + 7) * 68 + J + cc];
    }
    Tsh[p * 264 + r * 33 + cc] = s;
    __syncthreads();
    // step B: Y21 = -Y22 * T
    float s2 = 0.0f;
    {
      f4vec y0 = *reinterpret_cast<const f4vec*>(&Ysh[R * 68 + J + 8]);
      f4vec y1 = *reinterpret_cast<const f4vec*>(&Ysh[R * 68 + J + 12]);
      const float* Tc = &Tsh[p * 264 + cc];
      s2 += y0.x * Tc[0 * 33] + y0.y * Tc[1 * 33]
          + y0.z * Tc[2 * 33] + y0.w * Tc[3 * 33];
      s2 += y1.x * Tc[4 * 33] + y1.y * Tc[5 * 33]
          + y1.z * Tc[6 * 33] + y1.w * Tc[7 * 33];
    }
    __syncthreads();               // Tsh reuse at L2
    Ysh[R * 68 + J + cc] = -s2;
  }
  __syncthreads();

  // ---- L2: 2 pairs at 32-granularity; waves {0,1}->pair0, {2,3}->pair1. --
  {
    const int p = t >> 7, tid = t & 127;
    // step A: T = A21 * Y11  (16x16x16), 2 elems/thread
    float sa[2];
#pragma unroll
    for (int m = 0; m < 2; ++m) {
      const int E = tid + 128 * m, r = E >> 4, cc = E & 15;
      const int R = p * 32 + 16 + r, J = p * 32;
      float s = 0.0f;
#pragma unroll
      for (int k4 = 0; k4 < 4; ++k4) {
        f4vec a = *reinterpret_cast<const f4vec*>(&Ash[R * 68 + J + k4 * 4]);
        const int k = k4 * 4;
        s += a.x * Ysh[(J + k + 0) * 68 + J + cc]
           + a.y * Ysh[(J + k + 1) * 68 + J + cc]
           + a.z * Ysh[(J + k + 2) * 68 + J + cc]
           + a.w * Ysh[(J + k + 3) * 68 + J + cc];
      }
      sa[m] = s;
    }
#pragma unroll
    for (int m = 0; m < 2; ++m) {
      const int E = tid + 128 * m, r = E >> 4, cc = E & 15;
      Tsh[p * 528 + r * 33 + cc] = sa[m];
    }
    __syncthreads();
    // step B: Y21 = -Y22 * T
    float sb[2];
#pragma unroll
    for (int m = 0; m < 2; ++m) {
      const int E = tid + 128 * m, r = E >> 4, cc = E & 15;
      const int R = p * 32 + 16 + r, J = p * 32;
      float s = 0.0f;
      const float* Tc = &Tsh[p * 528 + cc];
#pragma unroll
      for (int k4 = 0; k4 < 4; ++k4) {
        f4vec y = *reinterpret_cast<const f4vec*>(&Ysh[R * 68 + J + 16 + k4 * 4]);
        const int k = k4 * 4;
        s += y.x * Tc[(k + 0) * 33] + y.y * Tc[(k + 1) * 33]
           + y.z * Tc[(k + 2) * 33] + y.w * Tc[(k + 3) * 33];
      }
      sb[m] = s;
    }
    __syncthreads();               // Tsh reuse at L3
#pragma unroll
    for (int m = 0; m < 2; ++m) {
      const int E = tid + 128 * m, r = E >> 4, cc = E & 15;
      const int R = p * 32 + 16 + r, J = p * 32;
      Ysh[R * 68 + J + cc] = -sb[m];
    }
  }
  __syncthreads();

  // ---- L3: final pair (rows 32..63, cols 0..31), 4 elems/thread. ----
  {
    // step A: T = A21 * Y11  (32x32x32)
    float sa[4];
#pragma unroll
    for (int m = 0; m < 4; ++m) {
      const int E = t + 256 * m, r = E >> 5, cc = E & 31;
      const int R = 32 + r;
      float s = 0.0f;
#pragma unroll
      for (int k4 = 0; k4 < 8; ++k4) {
        f4vec a = *reinterpret_cast<const f4vec*>(&Ash[R * 68 + k4 * 4]);
        const int k = k4 * 4;
        s += a.x * Ysh[(k + 0) * 68 + cc] + a.y * Ysh[(k + 1) * 68 + cc]
           + a.z * Ysh[(k + 2) * 68 + cc] + a.w * Ysh[(k + 3) * 68 + cc];
      }
      sa[m] = s;
    }
#pragma unroll
    for (int m = 0; m < 4; ++m) {
      const int E = t + 256 * m, r = E >> 5, cc = E & 31;
      Tsh[r * 33 + cc] = sa[m];
    }
    __syncthreads();
    // step B: Y21 = -Y22 * T
    float sb[4];
#pragma unroll
    for (int m = 0; m < 4; ++m) {
      const int E = t + 256 * m, r = E >> 5, cc = E & 31;
      const int R = 32 + r;
      float s = 0.0f;
      const float* Tc = &Tsh[cc];
#pragma unroll
      for (int k4 = 0; k4 < 8; ++k4) {
        f4vec y = *reinterpret_cast<const f4vec*>(&Ysh[R * 68 + 32 + k4 * 4]);
        const int k = k4 * 4;
        s += y.x * Tc[(k + 0) * 33] + y.y * Tc[(k + 1) * 33]
           + y.z * Tc[(k + 2) * 33] + y.w * Tc[(k + 3) * 33];
      }
      sb[m] = s;
    }
#pragma unroll
    for (int m = 0; m < 4; ++m) {
      const int E = t + 256 * m, r = E >> 5, cc = E & 31;
      Ysh[(32 + r) * 68 + cc] = -sb[m];
    }
  }
  __syncthreads();

  // ---- Epilogue: Mb = bf16(inv_L - I), Cvec = inv_L @ mean. ----
  const size_t mb_base = (size_t)b * 4096;
#pragma unroll
  for (int m = 0; m < 16; ++m) {
    const int e = t + 256 * m, i = e >> 6, j = e & 63;
    float v = 0.0f;
    if (j <= i) {
      v = sqd_sh[i] * Ysh[i * 68 + j];
      if (j == i) v -= 1.0f;
    }
    Mb[mb_base + e] = (unsigned short)f2bf(v);
  }
  {
    const int i2 = t >> 2, g = t & 3;
    float pz = 0.0f;
#pragma unroll
    for (int s2 = 0; s2 < 16; ++s2) {
      const int cc = g + 4 * s2;
      pz += Ysh[i2 * 68 + cc] * mean_sh[cc];
    }
    pz += __shfl_xor(pz, 1);
    pz += __shfl_xor(pz, 2);
    if (g == 0) Cout[b * 64 + i2] = pz * sqd_sh[i2];
  }
}

// ---------------- Kernel 3: out = x + M@x - c*1^T  (LDS-free) --------------
// r14: nontemporal stores for `out` (write-once, never re-read) -> no
// L2/L3 write-allocate, x stays L3-resident for the duration of k3.
__global__ __launch_bounds__(256) void k_whiten(
    const float* __restrict__ x, const float* __restrict__ Cvec,
    const unsigned short* __restrict__ Mb, float* __restrict__ out) {
  const int b = blockIdx.y;
  const int t = threadIdx.x;
  const int wid = t >> 6, lane = t & 63;
  const int lo = lane & 31, hi = lane >> 5;

  s8vec mfrag[2][4];
  const unsigned short* Mbb = Mb + (size_t)b * 4096;
#pragma unroll
  for (int wr = 0; wr < 2; ++wr)
#pragma unroll
    for (int ks = 0; ks < 4; ++ks)
      mfrag[wr][ks] = *reinterpret_cast<const s8vec*>(
          Mbb + (32 * wr + lo) * 64 + ks * 16 + hi * 8);

  float cv[2][16];
  const float* cb = Cvec + b * 64;
#pragma unroll
  for (int wr = 0; wr < 2; ++wr)
#pragma unroll
    for (int r = 0; r < 16; ++r)
      cv[wr][r] = cb[32 * wr + (r & 3) + 8 * (r >> 2) + 4 * hi];

  const float* xb = x + (size_t)b * N_DIM * D_DIM;
  float* ob = out + (size_t)b * N_DIM * D_DIM;

#pragma unroll
  for (int n = 0; n < 2; ++n) {
    const int d0 = blockIdx.x * 256 + wid * 64 + n * 32;
    f16vec acc0, acc1;
#pragma unroll
    for (int r = 0; r < 16; ++r) { acc0[r] = 0.0f; acc1[r] = 0.0f; }

#pragma unroll
    for (int ks = 0; ks < 4; ++ks) {
      const float* colp = xb + (size_t)(16 * ks + 8 * hi) * D_DIM + d0 + lo;
      s8vec bf;
#pragma unroll
      for (int e = 0; e < 8; ++e) bf[e] = f2bf(colp[(size_t)e * D_DIM]);
      acc0 = __builtin_amdgcn_mfma_f32_32x32x16_bf16(mfrag[0][ks], bf, acc0, 0, 0, 0);
      acc1 = __builtin_amdgcn_mfma_f32_32x32x16_bf16(mfrag[1][ks], bf, acc1, 0, 0, 0);
    }

#pragma unroll
    for (int r = 0; r < 16; ++r) {
      const int row = (r & 3) + 8 * (r >> 2) + 4 * hi;
      const size_t off0 = (size_t)row * D_DIM + d0 + lo;
      __builtin_nontemporal_store(acc0[r] + xb[off0] - cv[0][r], &ob[off0]);
      const size_t off1 = (size_t)(row + 32) * D_DIM + d0 + lo;
      __builtin_nontemporal_store(acc1[r] + xb[off1] - cv[1][r], &ob[off1]);
    }
  }
}

extern "C" void kernel_launch(void* const* d_in, const int* in_sizes, int n_in,
                              void* d_out, int out_size, void* d_ws,
                              size_t ws_size, hipStream_t stream) {
  const float* x = (const float*)d_in[0];
  float* out = (float*)d_out;
  char* ws = (char*)d_ws;

  float* Spart = (float*)ws;                            // 8 MB
  float* meanPart = (float*)(ws + 8388608);             // 128 KB
  float* Cout = (float*)(ws + 8519680);                 // 16 KB
  unsigned short* Mb = (unsigned short*)(ws + 8536064); // 512 KB

  k_cov_partial<<<dim3(SPLIT, B_DIM), 256, 0, stream>>>(x, Spart, meanPart);
  k_chol_inv<<<dim3(B_DIM), 256, 0, stream>>>(Spart, meanPart, Mb, Cout);
  k_whiten<<<dim3(D_DIM / 256, B_DIM), 256, 0, stream>>>(x, Cout, Mb, out);
}